// Round 4
// baseline (86.903 us; speedup 1.0000x reference)
//
#include <hip/hip_runtime.h>

// MultiStageFIRFilter: y = x + sum_{a=1..20} x_a, x_a = FIR25(x_{a-1}) / a
// FIR taps = mc (25 coefs) linearly interpolated per-sample between frames
// (frame period P=80, last frame replicated).
//
// One kernel. Each block: TILE=500 outputs + HALO=480 left halo (20 iters x
// 24-sample cone), whole cascade in double-buffered LDS, one barrier per
// Taylor iteration. Coefs interpolated once into registers (reused 20x).
// R2 change: 2 samples/thread (512-thr blocks) -> cm regs 100->50, est ~95
// VGPR -> ~5 waves/SIMD (vs 2.5), shorter per-wave FMA bursts. Same FLOPs.

#define NTAP   25
#define PFRAME 80
#define NFR    500
#define NTAYLOR 20
#define TILE   500
#define HALO   480              // NTAYLOR * 24
#define SAMP   (TILE + HALO)    // 980 samples per block
#define NCH    (SAMP / 2)       // 490 active threads (2 samples each)
#define PAD    24               // left zero-pad inside LDS buffer
#define BUFN   (PAD + SAMP + 4) // 1008 floats

__global__ __launch_bounds__(512, 4) void msfir_kernel(
    const float* __restrict__ x, const float* __restrict__ mc,
    float* __restrict__ y, int T) {
  __shared__ __align__(16) float buf[2][BUFN];
  const int tid  = threadIdx.x;
  const int tile = blockIdx.x;
  const int b    = blockIdx.y;
  const int T0   = tile * TILE;
  const int base = T0 - HALO;          // global t of local sample 0
  if (tid < PAD) { buf[0][tid] = 0.0f; buf[1][tid] = 0.0f; }

  const bool active = tid < NCH;
  const int cs = base + tid * 2;       // global t of this thread's 2 samples

  float yacc[2] = {0.f, 0.f};
  float cm[2][NTAP];                   // per-sample interpolated taps (regs)

  if (active) {
    // ---- load input chunk (t<0 -> 0, matches reference left zero-pad) ----
    float2 xv;
    if (cs >= 0) {
      xv = *reinterpret_cast<const float2*>(&x[(size_t)b * T + cs]);
    } else {
      xv = make_float2(0.f, 0.f);      // chunk fully <0 (HALO%2==0)
    }
    *reinterpret_cast<float2*>(&buf[0][PAD + tid * 2]) = xv;
    yacc[0] = xv.x; yacc[1] = xv.y;

    // ---- interpolated coefficients (cs even, P=80 even -> the 2 samples
    //      never straddle a frame boundary) ----
    const int csc = cs < 0 ? 0 : cs;   // coefs for t<0 samples are irrelevant
    const int n0 = csc / PFRAME;
    int n1 = n0 + 1; if (n1 >= NFR) n1 = NFR - 1;   // last frame replicated
    const float* __restrict__ r0 = &mc[((size_t)b * NFR + n0) * NTAP];
    const float* __restrict__ r1 = &mc[((size_t)b * NFR + n1) * NTAP];
    const float w0 = (float)(csc % PFRAME) * (1.0f / PFRAME);
    #pragma unroll
    for (int m = 0; m < NTAP; ++m) {
      const float a0 = r0[m];
      const float d  = r1[m] - a0;
      cm[0][m] = fmaf(w0, d, a0);
      cm[1][m] = fmaf(w0 + (1.0f / PFRAME), d, a0);
    }
  }
  __syncthreads();

  // ---- Taylor cascade: 20 serial FIR passes, double-buffered LDS ----
  int cur = 0;
  #pragma unroll 1
  for (int a = 1; a <= NTAYLOR; ++a) {
    const float inv = 1.0f / (float)a;
    if (active) {
      float win[PAD + 2];              // x[cs-24 .. cs+1], 8B-aligned reads
      #pragma unroll
      for (int k = 0; k < 13; ++k) {
        const float2 v =
            *reinterpret_cast<const float2*>(&buf[cur][tid * 2 + k * 2]);
        win[k*2+0] = v.x; win[k*2+1] = v.y;
      }
      float o0 = 0.f, o1 = 0.f;
      #pragma unroll
      for (int m = 0; m < NTAP; ++m) {          // out[t]=sum_m x[t-m]*cm[m]
        o0 = fmaf(win[PAD + 0 - m], cm[0][m], o0);
        o1 = fmaf(win[PAD + 1 - m], cm[1][m], o1);
      }
      o0 *= inv; o1 *= inv;
      yacc[0] += o0; yacc[1] += o1;
      *reinterpret_cast<float2*>(&buf[cur ^ 1][PAD + tid * 2]) =
          make_float2(o0, o1);
    }
    __syncthreads();                    // one barrier per iteration
    cur ^= 1;
  }

  // ---- write valid region only (halo discarded) ----
  if (active && cs >= T0) {
    *reinterpret_cast<float2*>(&y[(size_t)b * T + cs]) =
        make_float2(yacc[0], yacc[1]);
  }
}

extern "C" void kernel_launch(void* const* d_in, const int* in_sizes, int n_in,
                              void* d_out, int out_size, void* d_ws, size_t ws_size,
                              hipStream_t stream) {
  const float* x  = (const float*)d_in[0];
  const float* mc = (const float*)d_in[1];
  float* y = (float*)d_out;
  const int T = NFR * PFRAME;           // 40000
  const int B = in_sizes[0] / T;        // 8
  dim3 grid(T / TILE, B);               // (80, 8) = 640 blocks
  msfir_kernel<<<grid, 512, 0, stream>>>(x, mc, y, T);
}

// Round 5
// 80.822 us; speedup vs baseline: 1.0752x; 1.0752x over previous
//
#include <hip/hip_runtime.h>

// MultiStageFIRFilter: y = x + sum_{a=1..20} x_a, x_a = FIR25(x_{a-1}) / a
// FIR taps = mc (25 coefs) linearly interpolated per-sample between frames
// (frame period P=80, last frame replicated).
//
// Design: one kernel. Each block owns TILE=500 outputs + HALO=480 left halo
// (20 iters x 24-sample cone). Whole cascade runs in LDS (double-buffered),
// one __syncthreads per Taylor iteration. Per-sample interpolated coefs are
// precomputed once into registers (shared across all 20 iterations).
//
// R4 A/B result: 2 samples/thread (512 thr) = 86.9us vs this 4-sample
// variant = 81.3us -> reverted. (More waves/block + 2x LDS instruction
// count hurt; VALU issue was never the constraint at 2.5 waves/SIMD.)

#define NTAP   25
#define PFRAME 80
#define NFR    500
#define NTAYLOR 20
#define TILE   500
#define HALO   480              // NTAYLOR * 24
#define SAMP   (TILE + HALO)    // 980 samples per block
#define NCH    (SAMP / 4)       // 245 active threads (4 samples each)
#define PAD    24               // left zero-pad inside LDS buffer
#define BUFN   (PAD + SAMP + 4) // 1008 floats -> rows stay 16B aligned

__global__ __launch_bounds__(256) void msfir_kernel(
    const float* __restrict__ x, const float* __restrict__ mc,
    float* __restrict__ y, int T) {
  __shared__ __align__(16) float buf[2][BUFN];
  const int tid  = threadIdx.x;
  const int tile = blockIdx.x;
  const int b    = blockIdx.y;
  const int T0   = tile * TILE;
  const int base = T0 - HALO;          // global t of local sample 0
  // zero the pad once; garbage it could otherwise feed stays in the halo,
  // but zeroing makes that unconditional.
  if (tid < PAD) { buf[0][tid] = 0.0f; buf[1][tid] = 0.0f; }

  const bool active = tid < NCH;
  const int cs = base + tid * 4;       // global t of this thread's chunk

  float yacc[4] = {0.f, 0.f, 0.f, 0.f};
  float cm[4][NTAP];                   // per-sample interpolated taps (regs)

  if (active) {
    // ---- load input chunk (t<0 -> 0, matches reference left zero-pad) ----
    float4 xv;
    if (cs >= 0) {
      xv = *reinterpret_cast<const float4*>(&x[(size_t)b * T + cs]);
    } else {
      xv = make_float4(0.f, 0.f, 0.f, 0.f);   // chunk fully <0 (HALO%4==0)
    }
    *reinterpret_cast<float4*>(&buf[0][PAD + tid * 4]) = xv;
    yacc[0] = xv.x; yacc[1] = xv.y; yacc[2] = xv.z; yacc[3] = xv.w;

    // ---- precompute interpolated coefficients (chunk shares one frame:
    //      cs%4==0 and 80%4==0 -> no frame-boundary straddle) ----
    const int csc = cs < 0 ? 0 : cs;   // coefs for t<0 samples are irrelevant
    const int n0 = csc / PFRAME;
    int n1 = n0 + 1; if (n1 >= NFR) n1 = NFR - 1;   // last frame replicated
    const float* __restrict__ r0 = &mc[((size_t)b * NFR + n0) * NTAP];
    const float* __restrict__ r1 = &mc[((size_t)b * NFR + n1) * NTAP];
    const float w0 = (float)(csc % PFRAME) * (1.0f / PFRAME);
    #pragma unroll
    for (int m = 0; m < NTAP; ++m) {
      const float a0 = r0[m];
      const float d  = r1[m] - a0;
      #pragma unroll
      for (int j = 0; j < 4; ++j) {
        const float w = w0 + (float)j * (1.0f / PFRAME);
        cm[j][m] = fmaf(w, d, a0);
      }
    }
  }
  __syncthreads();

  // ---- Taylor cascade: 20 serial FIR passes, double-buffered LDS ----
  int cur = 0;
  #pragma unroll 1
  for (int a = 1; a <= NTAYLOR; ++a) {
    const float inv = 1.0f / (float)a;
    if (active) {
      float win[PAD + 4];              // x[cs-24 .. cs+3], 16B-aligned reads
      #pragma unroll
      for (int k = 0; k < 7; ++k) {
        const float4 v =
            *reinterpret_cast<const float4*>(&buf[cur][tid * 4 + k * 4]);
        win[k*4+0] = v.x; win[k*4+1] = v.y; win[k*4+2] = v.z; win[k*4+3] = v.w;
      }
      float out[4];
      #pragma unroll
      for (int j = 0; j < 4; ++j) {
        float acc = 0.0f;
        #pragma unroll
        for (int m = 0; m < NTAP; ++m)         // out[t]=sum_m x[t-m]*cm[m]
          acc = fmaf(win[PAD + j - m], cm[j][m], acc);
        out[j] = acc * inv;
        yacc[j] += out[j];
      }
      *reinterpret_cast<float4*>(&buf[cur ^ 1][PAD + tid * 4]) =
          make_float4(out[0], out[1], out[2], out[3]);
    }
    __syncthreads();                    // one barrier per iteration
    cur ^= 1;
  }

  // ---- write valid region only (halo chunks discarded) ----
  if (active && cs >= T0) {
    *reinterpret_cast<float4*>(&y[(size_t)b * T + cs]) =
        make_float4(yacc[0], yacc[1], yacc[2], yacc[3]);
  }
}

extern "C" void kernel_launch(void* const* d_in, const int* in_sizes, int n_in,
                              void* d_out, int out_size, void* d_ws, size_t ws_size,
                              hipStream_t stream) {
  const float* x  = (const float*)d_in[0];
  const float* mc = (const float*)d_in[1];
  float* y = (float*)d_out;
  const int T = NFR * PFRAME;           // 40000
  const int B = in_sizes[0] / T;        // 8
  dim3 grid(T / TILE, B);               // (80, 8) = 640 blocks
  msfir_kernel<<<grid, 256, 0, stream>>>(x, mc, y, T);
}